// Round 1
// baseline (19531.856 us; speedup 1.0000x reference)
//
#include <hip/hip_runtime.h>
#include <math.h>

#define BB 64
#define TT 512
#define DD 128
#define HH 512

// One timestep. Grid: 256 WGs = 8 bgroups x 32 jslices, block 256.
// WG handles 8 batches x 16 columns x 4 gates.
// blockIdx mapping: jsl = blk & 31 (so each XCD's WGs share the same
// j-slices across all bgroups -> per-XCD U footprint ~512KB, L2-resident).
__global__ __launch_bounds__(256) void lstm_step(
    const float* __restrict__ x,
    const float* __restrict__ Wi_w, const float* __restrict__ Wi_b, const float* __restrict__ Ui_w,
    const float* __restrict__ Wf_w, const float* __restrict__ Wf_b, const float* __restrict__ Uf_w,
    const float* __restrict__ Wo_w, const float* __restrict__ Wo_b, const float* __restrict__ Uo_w,
    const float* __restrict__ Wg_w, const float* __restrict__ Wg_b, const float* __restrict__ Ug_w,
    const float* __restrict__ h_cur, float* __restrict__ h_nxt, float* __restrict__ cbuf,
    float* __restrict__ hs, float* __restrict__ fs, float* __restrict__ es, float* __restrict__ cds,
    int t)
{
    __shared__ float hl[8][HH];        // 16 KB: h rows for this bgroup
    __shared__ float xl[8][DD];        // 4 KB : x rows at time t
    __shared__ float preL[8][16][4];   // 2 KB : preactivations (i,f,o,g)

    const int tid  = threadIdx.x;
    const int jsl  = blockIdx.x & 31;
    const int bgrp = blockIdx.x >> 5;
    const int b0   = bgrp * 8;
    const int j0   = jsl * 16;

    // ---- stage h slice: 8 rows x 512 f32 = 1024 float4, 4 per thread ----
    {
        const float4* src = (const float4*)(h_cur + (size_t)b0 * HH);
        float4* dst = (float4*)(&hl[0][0]);
        #pragma unroll
        for (int i = 0; i < 4; ++i) dst[tid + 256 * i] = src[tid + 256 * i];
    }
    // ---- stage x rows: 8 x 128 f32 = 256 float4, 1 per thread ----
    {
        const int b = tid >> 5, d4 = tid & 31;
        const float4* src = (const float4*)(x + ((size_t)(b0 + b) * TT + t) * DD);
        ((float4*)&xl[b][0])[d4] = src[d4];
    }
    __syncthreads();

    // ---- each thread computes 2 gate preactivations for one (b, j) ----
    {
        const int b  = tid >> 5;           // 0..7
        const int j  = (tid >> 1) & 15;    // 0..15
        const int gp = tid & 1;            // 0: (i,f)  1: (o,g)
        const int jj = j0 + j;

        const float* U0 = gp ? Uo_w : Ui_w;
        const float* U1 = gp ? Ug_w : Uf_w;
        const float* W0 = gp ? Wo_w : Wi_w;
        const float* W1 = gp ? Wg_w : Wf_w;
        float acc0 = (gp ? Wo_b : Wi_b)[jj];
        float acc1 = (gp ? Wg_b : Wf_b)[jj];

        const float4* u0 = (const float4*)(U0 + (size_t)jj * HH);
        const float4* u1 = (const float4*)(U1 + (size_t)jj * HH);
        const float4* hv = (const float4*)(&hl[b][0]);
        #pragma unroll 8
        for (int k = 0; k < HH / 4; ++k) {
            float4 h4 = hv[k];
            float4 a  = u0[k];
            float4 c  = u1[k];
            acc0 += h4.x * a.x + h4.y * a.y + h4.z * a.z + h4.w * a.w;
            acc1 += h4.x * c.x + h4.y * c.y + h4.z * c.z + h4.w * c.w;
        }
        const float4* w0 = (const float4*)(W0 + (size_t)jj * DD);
        const float4* w1 = (const float4*)(W1 + (size_t)jj * DD);
        const float4* xv = (const float4*)(&xl[b][0]);
        #pragma unroll 8
        for (int k = 0; k < DD / 4; ++k) {
            float4 x4 = xv[k];
            float4 a  = w0[k];
            float4 c  = w1[k];
            acc0 += x4.x * a.x + x4.y * a.y + x4.z * a.z + x4.w * a.w;
            acc1 += x4.x * c.x + x4.y * c.y + x4.z * c.z + x4.w * c.w;
        }
        preL[b][j][gp * 2 + 0] = acc0;   // [0]=i [1]=f [2]=o [3]=g
        preL[b][j][gp * 2 + 1] = acc1;
    }
    __syncthreads();

    // ---- pointwise: 128 threads, one (b, j) each ----
    if (tid < 128) {
        const int b  = tid >> 4;
        const int j  = tid & 15;
        const int jj = j0 + j;
        const int gb = b0 + b;

        const float pi = preL[b][j][0];
        const float pf = preL[b][j][1];
        const float po = preL[b][j][2];
        const float pg = preL[b][j][3];

        const float ig = 1.f / (1.f + __expf(-pi));
        const float fg = 1.f / (1.f + __expf(-pf));
        const float og = 1.f / (1.f + __expf(-po));
        const float gg = tanhf(pg);

        const size_t cidx = (size_t)gb * HH + jj;
        const float cp = cbuf[cidx];
        const float c  = fg * cp + ig * gg;
        const float th = tanhf(c);
        const float h  = og * th;
        const float e  = og * (1.f - th * th);

        const float uid = Ui_w[(size_t)jj * HH + jj];
        const float ufd = Uf_w[(size_t)jj * HH + jj];
        const float ugd = Ug_w[(size_t)jj * HH + jj];
        const float cd = cp * (fg * (1.f - fg)) * ufd
                       + ig * (1.f - gg * gg) * ugd
                       + gg * (ig * (1.f - ig)) * uid;

        cbuf[cidx]  = c;
        h_nxt[cidx] = h;

        const size_t oidx = ((size_t)gb * TT + t) * HH + jj;
        hs[oidx]  = h;
        fs[oidx]  = fg;
        es[oidx]  = e;
        cds[oidx] = cd;
    }
}

// ys[r] = dot(hs[r, :], out_w) + out_b ; one wave per row r = b*T + t
__global__ __launch_bounds__(256) void lstm_y(
    const float* __restrict__ hs, const float* __restrict__ out_w,
    const float* __restrict__ out_b, float* __restrict__ ys)
{
    const int wave = threadIdx.x >> 6;
    const int lane = threadIdx.x & 63;
    const int r = blockIdx.x * 4 + wave;

    const float4* hv = (const float4*)(hs + (size_t)r * HH);
    const float4* wv = (const float4*)out_w;
    float acc = 0.f;
    #pragma unroll
    for (int i = 0; i < 2; ++i) {
        float4 h4 = hv[lane * 2 + i];
        float4 w4 = wv[lane * 2 + i];
        acc += h4.x * w4.x + h4.y * w4.y + h4.z * w4.z + h4.w * w4.w;
    }
    #pragma unroll
    for (int m = 32; m >= 1; m >>= 1) acc += __shfl_xor(acc, m, 64);
    if (lane == 0) ys[r] = acc + out_b[0];
}

extern "C" void kernel_launch(void* const* d_in, const int* in_sizes, int n_in,
                              void* d_out, int out_size, void* d_ws, size_t ws_size,
                              hipStream_t stream)
{
    const float* x    = (const float*)d_in[0];
    const float* Wi_w = (const float*)d_in[1];
    const float* Wi_b = (const float*)d_in[2];
    const float* Ui_w = (const float*)d_in[3];
    const float* Wf_w = (const float*)d_in[4];
    const float* Wf_b = (const float*)d_in[5];
    const float* Uf_w = (const float*)d_in[6];
    const float* Wo_w = (const float*)d_in[7];
    const float* Wo_b = (const float*)d_in[8];
    const float* Uo_w = (const float*)d_in[9];
    const float* Wg_w = (const float*)d_in[10];
    const float* Wg_b = (const float*)d_in[11];
    const float* Ug_w = (const float*)d_in[12];
    const float* out_w = (const float*)d_in[13];
    const float* out_b = (const float*)d_in[14];

    float* ys  = (float*)d_out;                     // [B*T]
    float* hs  = ys + (size_t)BB * TT;              // [B*T*H]
    float* fs  = hs + (size_t)BB * TT * HH;
    float* es  = fs + (size_t)BB * TT * HH;
    float* cds = es + (size_t)BB * TT * HH;

    float* hbuf0 = (float*)d_ws;                    // [B*H]
    float* hbuf1 = hbuf0 + (size_t)BB * HH;
    float* cbuf  = hbuf1 + (size_t)BB * HH;

    // h0 = 0, c0 = 0 every call (harness does not re-poison between replays)
    hipMemsetAsync(d_ws, 0, (size_t)3 * BB * HH * sizeof(float), stream);

    for (int t = 0; t < TT; ++t) {
        const float* hc = (t & 1) ? hbuf1 : hbuf0;
        float*       hn = (t & 1) ? hbuf0 : hbuf1;
        lstm_step<<<256, 256, 0, stream>>>(
            x, Wi_w, Wi_b, Ui_w, Wf_w, Wf_b, Uf_w, Wo_w, Wo_b, Uo_w,
            Wg_w, Wg_b, Ug_w, hc, hn, cbuf, hs, fs, es, cds, t);
    }
    lstm_y<<<(BB * TT) / 4, 256, 0, stream>>>(hs, out_w, out_b, ys);
}

// Round 2
// 15599.287 us; speedup vs baseline: 1.2521x; 1.2521x over previous
//
#include <hip/hip_runtime.h>
#include <math.h>

#define BB 64
#define TT 512
#define DD 128
#define HH 512
#define NWG 256

// ---------------------------------------------------------------------------
// Phase A: x-projections. xi/xf/xo/xg[b][t][jj] = x[b][t][:] . W_g[jj][:] + b_g[jj]
// Grid 256 x 512. Wave w: gate g = w>>1, jj-half = w&1. lane = jj within 64-block.
// W row (128 floats) register-resident per lane; x row is wave-uniform (s_load).
// ---------------------------------------------------------------------------
__global__ __launch_bounds__(512) void xproj_kernel(
    const float* __restrict__ x,
    const float* __restrict__ Wi_w, const float* __restrict__ Wi_b,
    const float* __restrict__ Wf_w, const float* __restrict__ Wf_b,
    const float* __restrict__ Wo_w, const float* __restrict__ Wo_b,
    const float* __restrict__ Wg_w, const float* __restrict__ Wg_b,
    float* __restrict__ xi, float* __restrict__ xf,
    float* __restrict__ xo, float* __restrict__ xg)
{
    const int tid  = threadIdx.x;
    const int w    = tid >> 6;
    const int lane = tid & 63;
    const int g     = w >> 1;
    const int jhalf = w & 1;
    const int bt0   = blockIdx.x * 128;

    const float* W  = (g == 0) ? Wi_w : (g == 1) ? Wf_w : (g == 2) ? Wo_w : Wg_w;
    const float* Bv = (g == 0) ? Wi_b : (g == 1) ? Wf_b : (g == 2) ? Wo_b : Wg_b;
    float* out      = (g == 0) ? xi   : (g == 1) ? xf   : (g == 2) ? xo   : xg;

    for (int blk = 0; blk < 4; ++blk) {
        const int jj = jhalf * 256 + blk * 64 + lane;
        float4 wr[32];
        const float4* wsrc = (const float4*)(W + (size_t)jj * DD);
        #pragma unroll
        for (int i = 0; i < 32; ++i) wr[i] = wsrc[i];
        const float bias = Bv[jj];

        for (int bt = bt0; bt < bt0 + 128; ++bt) {
            const float4* xr = (const float4*)(x + (size_t)bt * DD);  // wave-uniform
            float acc = bias;
            #pragma unroll
            for (int i = 0; i < 32; ++i) {
                const float4 xv = xr[i];
                acc += xv.x * wr[i].x + xv.y * wr[i].y + xv.z * wr[i].z + xv.w * wr[i].w;
            }
            out[(size_t)bt * HH + jj] = acc;
        }
    }
}

// ---------------------------------------------------------------------------
// Persistent recurrence. 256 WGs x 512 thr, 1 WG/CU (co-resident by capacity).
// WG owns jj pair p = (wg&7)*32 + (wg>>3) (XCD-swizzled so the 8 WGs sharing an
// output 64B line sit on one XCD's L2). lane = batch. Wave w covers K-slice
// [w*64, w*64+64). U_T in LDS, h ping-pong in d_ws as h_T[k][b].
// ---------------------------------------------------------------------------
__global__ __launch_bounds__(512) void lstm_persist(
    const float* __restrict__ Ui_w, const float* __restrict__ Uf_w,
    const float* __restrict__ Uo_w, const float* __restrict__ Ug_w,
    float* __restrict__ b_i, float* __restrict__ b_f,   // xi->hs, xf->fs
    float* __restrict__ b_o, float* __restrict__ b_g,   // xo->es, xg->cds
    float* __restrict__ hT0, float* __restrict__ hT1,
    int* __restrict__ cnt)
{
    __shared__ float UT[HH][8];        // 16 KB  UT[k][r], r = jp*4 + g
    __shared__ float red[8][8][64];    // 16 KB  [k-wave][r][lane]

    const int tid  = threadIdx.x;
    const int w    = tid >> 6;
    const int lane = tid & 63;
    const int wg   = blockIdx.x;
    const int pair = ((wg & 7) << 5) | (wg >> 3);
    const int jj0  = pair << 1;

    {
        const float* Us[4] = {Ui_w, Uf_w, Uo_w, Ug_w};
        #pragma unroll
        for (int r = 0; r < 8; ++r) {
            const int jp = r >> 2, g = r & 3;
            UT[tid][r] = Us[g][(size_t)(jj0 + jp) * HH + tid];
        }
    }

    // pointwise state (waves 0/1 only): c register + U diagonals
    float creg = 0.f, uid = 0.f, ufd = 0.f, ugd = 0.f;
    const int jp = (w < 2) ? w : 0;
    const int jj = jj0 + jp;
    if (w < 2) {
        uid = Ui_w[(size_t)jj * HH + jj];
        ufd = Uf_w[(size_t)jj * HH + jj];
        ugd = Ug_w[(size_t)jj * HH + jj];
    }
    __syncthreads();

    const int k0 = w << 6;

    for (int t = 0; t < TT; ++t) {
        const float* hsrc = (t & 1) ? hT1 : hT0;
        float*       hdst = (t & 1) ? hT0 : hT1;

        // prefetch x-projections early (latency hides under k-loop)
        float xpi = 0.f, xpf = 0.f, xpo = 0.f, xpg = 0.f;
        size_t adr = 0;
        if (w < 2) {
            adr = ((size_t)lane * TT + t) * HH + jj;
            xpi = b_i[adr]; xpf = b_f[adr]; xpo = b_o[adr]; xpg = b_g[adr];
        }

        float acc[8] = {0.f, 0.f, 0.f, 0.f, 0.f, 0.f, 0.f, 0.f};
        for (int kc = 0; kc < 64; kc += 8) {
            float hbuf[8];
            #pragma unroll
            for (int i = 0; i < 8; ++i)
                hbuf[i] = hsrc[(size_t)(k0 + kc + i) * 64 + lane];
            #pragma unroll
            for (int i = 0; i < 8; ++i) {
                const float4 u0 = *(const float4*)&UT[k0 + kc + i][0];
                const float4 u1 = *(const float4*)&UT[k0 + kc + i][4];
                const float hv = hbuf[i];
                acc[0] += u0.x * hv; acc[1] += u0.y * hv;
                acc[2] += u0.z * hv; acc[3] += u0.w * hv;
                acc[4] += u1.x * hv; acc[5] += u1.y * hv;
                acc[6] += u1.z * hv; acc[7] += u1.w * hv;
            }
        }
        #pragma unroll
        for (int r = 0; r < 8; ++r) red[w][r][lane] = acc[r];
        __syncthreads();

        if (w < 2) {
            float pre[4];
            #pragma unroll
            for (int g = 0; g < 4; ++g) {
                float s = 0.f;
                #pragma unroll
                for (int wk = 0; wk < 8; ++wk) s += red[wk][jp * 4 + g][lane];
                pre[g] = s;
            }
            const float pi = xpi + pre[0];
            const float pf = xpf + pre[1];
            const float po = xpo + pre[2];
            const float pg = xpg + pre[3];

            const float ig = __fdividef(1.f, 1.f + __expf(-pi));
            const float fg = __fdividef(1.f, 1.f + __expf(-pf));
            const float og = __fdividef(1.f, 1.f + __expf(-po));
            const float tg = __expf(-2.f * fmaxf(pg, -40.f));
            const float gg = __fdividef(1.f - tg, 1.f + tg);

            const float cp = creg;
            const float c  = fg * cp + ig * gg;
            creg = c;
            const float tc = __expf(-2.f * fmaxf(c, -40.f));
            const float th = __fdividef(1.f - tc, 1.f + tc);
            const float h  = og * th;
            const float e  = og * (1.f - th * th);
            const float cd = cp * (fg * (1.f - fg)) * ufd
                           + ig * (1.f - gg * gg) * ugd
                           + gg * (ig * (1.f - ig)) * uid;

            b_i[adr] = h;   // hs
            b_f[adr] = fg;  // fs
            b_o[adr] = e;   // es
            b_g[adr] = cd;  // cds
            hdst[(size_t)jj * 64 + lane] = h;
        }

        // ---- grid barrier (per-step counter) ----
        __syncthreads();   // drains vmcnt: all waves' stores are in L2
        if (tid == 0) {
            __threadfence();   // release
            __hip_atomic_fetch_add(&cnt[t], 1, __ATOMIC_RELAXED, __HIP_MEMORY_SCOPE_AGENT);
            while (__hip_atomic_load(&cnt[t], __ATOMIC_RELAXED, __HIP_MEMORY_SCOPE_AGENT) < NWG)
                __builtin_amdgcn_s_sleep(2);
            __threadfence();   // acquire
        }
        __syncthreads();
    }
}

// ys[r] = dot(hs[r,:], out_w) + out_b ; one wave per row r = b*T + t
__global__ __launch_bounds__(256) void lstm_y(
    const float* __restrict__ hs, const float* __restrict__ out_w,
    const float* __restrict__ out_b, float* __restrict__ ys)
{
    const int wave = threadIdx.x >> 6;
    const int lane = threadIdx.x & 63;
    const int r = blockIdx.x * 4 + wave;

    const float4* hv = (const float4*)(hs + (size_t)r * HH);
    const float4* wv = (const float4*)out_w;
    float acc = 0.f;
    #pragma unroll
    for (int i = 0; i < 2; ++i) {
        float4 h4 = hv[lane * 2 + i];
        float4 w4 = wv[lane * 2 + i];
        acc += h4.x * w4.x + h4.y * w4.y + h4.z * w4.z + h4.w * w4.w;
    }
    #pragma unroll
    for (int m = 32; m >= 1; m >>= 1) acc += __shfl_xor(acc, m, 64);
    if (lane == 0) ys[r] = acc + out_b[0];
}

extern "C" void kernel_launch(void* const* d_in, const int* in_sizes, int n_in,
                              void* d_out, int out_size, void* d_ws, size_t ws_size,
                              hipStream_t stream)
{
    const float* x    = (const float*)d_in[0];
    const float* Wi_w = (const float*)d_in[1];
    const float* Wi_b = (const float*)d_in[2];
    const float* Ui_w = (const float*)d_in[3];
    const float* Wf_w = (const float*)d_in[4];
    const float* Wf_b = (const float*)d_in[5];
    const float* Uf_w = (const float*)d_in[6];
    const float* Wo_w = (const float*)d_in[7];
    const float* Wo_b = (const float*)d_in[8];
    const float* Uo_w = (const float*)d_in[9];
    const float* Wg_w = (const float*)d_in[10];
    const float* Wg_b = (const float*)d_in[11];
    const float* Ug_w = (const float*)d_in[12];
    const float* out_w = (const float*)d_in[13];
    const float* out_b = (const float*)d_in[14];

    float* ys  = (float*)d_out;                     // [B*T]
    float* hs  = ys + (size_t)BB * TT;              // [B*T*H]
    float* fs  = hs + (size_t)BB * TT * HH;
    float* es  = fs + (size_t)BB * TT * HH;
    float* cds = es + (size_t)BB * TT * HH;

    float* hT0 = (float*)d_ws;                      // [H][B]
    float* hT1 = hT0 + (size_t)HH * BB;
    int*   cnt = (int*)(hT1 + (size_t)HH * BB);     // [T]

    // zero h ping-pong + barrier counters every call (graph-replay safe)
    hipMemsetAsync(d_ws, 0, (size_t)2 * HH * BB * sizeof(float) + TT * sizeof(int), stream);

    // Phase A: x projections into output buffers (scratch)
    xproj_kernel<<<256, 512, 0, stream>>>(x, Wi_w, Wi_b, Wf_w, Wf_b,
                                          Wo_w, Wo_b, Wg_w, Wg_b,
                                          hs, fs, es, cds);

    // Phase B: persistent recurrence
    lstm_persist<<<NWG, 512, 0, stream>>>(Ui_w, Uf_w, Uo_w, Ug_w,
                                          hs, fs, es, cds, hT0, hT1, cnt);

    // Phase C: y projection
    lstm_y<<<(BB * TT) / 4, 256, 0, stream>>>(hs, out_w, out_b, ys);
}

// Round 3
// 9354.814 us; speedup vs baseline: 2.0879x; 1.6675x over previous
//
#include <hip/hip_runtime.h>
#include <math.h>

#define BB 64
#define TT 512
#define DD 128
#define HH 512
#define NWG 128

// ---------------------------------------------------------------------------
// Pre-kernel: transpose U into utT[quad][k][16], r = jp*4 + g, quad owns
// jj = quad*4 .. quad*4+3. Enables uniform (scalar) loads in the k-loop.
// ---------------------------------------------------------------------------
__global__ __launch_bounds__(256) void uT_kernel(
    const float* __restrict__ Ui_w, const float* __restrict__ Uf_w,
    const float* __restrict__ Uo_w, const float* __restrict__ Ug_w,
    float* __restrict__ utT)
{
    const int q = blockIdx.x;
    const int jj0 = q << 2;
    for (int k = threadIdx.x; k < HH; k += 256) {
        float v[16];
        #pragma unroll
        for (int r = 0; r < 16; ++r) {
            const int jp = r >> 2, g = r & 3;
            const float* U = (g == 0) ? Ui_w : (g == 1) ? Uf_w : (g == 2) ? Uo_w : Ug_w;
            v[r] = U[(size_t)(jj0 + jp) * HH + k];
        }
        float4* dst = (float4*)(utT + ((size_t)q * HH + k) * 16);
        dst[0] = make_float4(v[0], v[1], v[2], v[3]);
        dst[1] = make_float4(v[4], v[5], v[6], v[7]);
        dst[2] = make_float4(v[8], v[9], v[10], v[11]);
        dst[3] = make_float4(v[12], v[13], v[14], v[15]);
    }
}

// ---------------------------------------------------------------------------
// Phase A: x-projections (unchanged from round 2).
// ---------------------------------------------------------------------------
__global__ __launch_bounds__(512) void xproj_kernel(
    const float* __restrict__ x,
    const float* __restrict__ Wi_w, const float* __restrict__ Wi_b,
    const float* __restrict__ Wf_w, const float* __restrict__ Wf_b,
    const float* __restrict__ Wo_w, const float* __restrict__ Wo_b,
    const float* __restrict__ Wg_w, const float* __restrict__ Wg_b,
    float* __restrict__ xi, float* __restrict__ xf,
    float* __restrict__ xo, float* __restrict__ xg)
{
    const int tid  = threadIdx.x;
    const int w    = tid >> 6;
    const int lane = tid & 63;
    const int g     = w >> 1;
    const int jhalf = w & 1;
    const int bt0   = blockIdx.x * 128;

    const float* W  = (g == 0) ? Wi_w : (g == 1) ? Wf_w : (g == 2) ? Wo_w : Wg_w;
    const float* Bv = (g == 0) ? Wi_b : (g == 1) ? Wf_b : (g == 2) ? Wo_b : Wg_b;
    float* out      = (g == 0) ? xi   : (g == 1) ? xf   : (g == 2) ? xo   : xg;

    for (int blk = 0; blk < 4; ++blk) {
        const int jj = jhalf * 256 + blk * 64 + lane;
        float4 wr[32];
        const float4* wsrc = (const float4*)(W + (size_t)jj * DD);
        #pragma unroll
        for (int i = 0; i < 32; ++i) wr[i] = wsrc[i];
        const float bias = Bv[jj];

        for (int bt = bt0; bt < bt0 + 128; ++bt) {
            const float4* xr = (const float4*)(x + (size_t)bt * DD);
            float acc = bias;
            #pragma unroll
            for (int i = 0; i < 32; ++i) {
                const float4 xv = xr[i];
                acc += xv.x * wr[i].x + xv.y * wr[i].y + xv.z * wr[i].z + xv.w * wr[i].w;
            }
            out[(size_t)bt * HH + jj] = acc;
        }
    }
}

// ---------------------------------------------------------------------------
// Persistent recurrence. 128 WGs x 512 thr (all co-resident). WG owns quad
// ((wg&7)<<4)|(wg>>3)  -> jj0 = quad*4 (XCD-swizzled: quads sharing a 64B
// output line land on the same XCD for L2 write merging).
// Wave w covers k in [w*64, w*64+64); U slice via uniform scalar loads.
// h exchanged via agent-scope relaxed atomics (MALL), outputs via normal
// cached stores. Grid barrier: one relaxed agent atomic per WG, no fences.
// ---------------------------------------------------------------------------
__global__ __launch_bounds__(512) void lstm_persist(
    const float* __restrict__ utT,
    const float* __restrict__ Ui_w, const float* __restrict__ Uf_w,
    const float* __restrict__ Ug_w,
    float* __restrict__ b_i, float* __restrict__ b_f,   // xi->hs, xf->fs
    float* __restrict__ b_o, float* __restrict__ b_g,   // xo->es, xg->cds
    float* __restrict__ hT0, float* __restrict__ hT1,
    int* __restrict__ cnt)
{
    __shared__ float red[8][16][64];   // 32 KB partial sums

    const int tid  = threadIdx.x;
    const int w    = tid >> 6;
    const int lane = tid & 63;
    const int wg   = blockIdx.x;
    const int quad = ((wg & 7) << 4) | (wg >> 3);
    const int jj0  = quad << 2;
    const int k0   = w << 6;

    // wave-uniform scalar base for this wave's U slice (forces s_load path)
    const unsigned uoff = (unsigned)__builtin_amdgcn_readfirstlane(k0 << 4);
    const float4* up4 = (const float4*)(utT + (size_t)quad * (HH * 16) + uoff);

    // pointwise state (waves 0..3): c in register + U diagonals
    float creg = 0.f, uid = 0.f, ufd = 0.f, ugd = 0.f;
    const int jp = (w < 4) ? w : 0;
    const int jj = jj0 + jp;
    if (w < 4) {
        uid = Ui_w[(size_t)jj * HH + jj];
        ufd = Uf_w[(size_t)jj * HH + jj];
        ugd = Ug_w[(size_t)jj * HH + jj];
    }

    for (int t = 0; t < TT; ++t) {
        float* hsrc = (t & 1) ? hT1 : hT0;
        float* hdst = (t & 1) ? hT0 : hT1;

        // prefetch x-projections (normal cached loads, hide under k-loop)
        float xpi = 0.f, xpf = 0.f, xpo = 0.f, xpg = 0.f;
        size_t adr = 0;
        if (w < 4) {
            adr = ((size_t)lane * TT + t) * HH + jj;
            xpi = b_i[adr]; xpf = b_f[adr]; xpo = b_o[adr]; xpg = b_g[adr];
        }

        // ---- issue the wave's entire h k-slice (64 coalesced MALL loads) ----
        float hreg[64];
        #pragma unroll
        for (int i = 0; i < 64; ++i)
            hreg[i] = __hip_atomic_load(&hsrc[(size_t)(k0 + i) * 64 + lane],
                                        __ATOMIC_RELAXED, __HIP_MEMORY_SCOPE_AGENT);

        float acc[16];
        #pragma unroll
        for (int r = 0; r < 16; ++r) acc[r] = 0.f;

        #pragma unroll
        for (int i = 0; i < 64; ++i) {
            const float4 u0 = up4[(i << 2) + 0];
            const float4 u1 = up4[(i << 2) + 1];
            const float4 u2 = up4[(i << 2) + 2];
            const float4 u3 = up4[(i << 2) + 3];
            const float hv = hreg[i];
            acc[0]  = fmaf(u0.x, hv, acc[0]);
            acc[1]  = fmaf(u0.y, hv, acc[1]);
            acc[2]  = fmaf(u0.z, hv, acc[2]);
            acc[3]  = fmaf(u0.w, hv, acc[3]);
            acc[4]  = fmaf(u1.x, hv, acc[4]);
            acc[5]  = fmaf(u1.y, hv, acc[5]);
            acc[6]  = fmaf(u1.z, hv, acc[6]);
            acc[7]  = fmaf(u1.w, hv, acc[7]);
            acc[8]  = fmaf(u2.x, hv, acc[8]);
            acc[9]  = fmaf(u2.y, hv, acc[9]);
            acc[10] = fmaf(u2.z, hv, acc[10]);
            acc[11] = fmaf(u2.w, hv, acc[11]);
            acc[12] = fmaf(u3.x, hv, acc[12]);
            acc[13] = fmaf(u3.y, hv, acc[13]);
            acc[14] = fmaf(u3.z, hv, acc[14]);
            acc[15] = fmaf(u3.w, hv, acc[15]);
        }
        #pragma unroll
        for (int r = 0; r < 16; ++r) red[w][r][lane] = acc[r];
        __syncthreads();

        if (w < 4) {
            float pre[4];
            #pragma unroll
            for (int g = 0; g < 4; ++g) {
                float s = 0.f;
                #pragma unroll
                for (int wk = 0; wk < 8; ++wk) s += red[wk][(jp << 2) + g][lane];
                pre[g] = s;
            }
            const float pi = xpi + pre[0];
            const float pf = xpf + pre[1];
            const float po = xpo + pre[2];
            const float pg = xpg + pre[3];

            const float ig = __fdividef(1.f, 1.f + __expf(-pi));
            const float fg = __fdividef(1.f, 1.f + __expf(-pf));
            const float og = __fdividef(1.f, 1.f + __expf(-po));
            const float tg = __expf(-2.f * fmaxf(pg, -40.f));
            const float gg = __fdividef(1.f - tg, 1.f + tg);

            const float cp = creg;
            const float c  = fg * cp + ig * gg;
            creg = c;
            const float tc = __expf(-2.f * fmaxf(c, -40.f));
            const float th = __fdividef(1.f - tc, 1.f + tc);
            const float h  = og * th;
            const float e  = og * (1.f - th * th);
            const float cd = cp * (fg * (1.f - fg)) * ufd
                           + ig * (1.f - gg * gg) * ugd
                           + gg * (ig * (1.f - ig)) * uid;

            b_i[adr] = h;   // hs   (normal cached stores: merge in L2)
            b_f[adr] = fg;  // fs
            b_o[adr] = e;   // es
            b_g[adr] = cd;  // cds

            // h export: device-coherent store (bypasses L2 to MALL)
            __hip_atomic_store(&hdst[(size_t)jj * 64 + lane], h,
                               __ATOMIC_RELAXED, __HIP_MEMORY_SCOPE_AGENT);
        }

        // ---- grid barrier: arrive + spin (no cache-walk fences) ----
        __syncthreads();   // all waves' stores drained (compiler waits vmcnt)
        if (tid == 0) {
            __hip_atomic_fetch_add(&cnt[t], 1, __ATOMIC_RELAXED,
                                   __HIP_MEMORY_SCOPE_AGENT);
            while (__hip_atomic_load(&cnt[t], __ATOMIC_RELAXED,
                                     __HIP_MEMORY_SCOPE_AGENT) < NWG)
                __builtin_amdgcn_s_sleep(2);
        }
        __syncthreads();
    }
}

// ys[r] = dot(hs[r,:], out_w) + out_b ; one wave per row r = b*T + t
__global__ __launch_bounds__(256) void lstm_y(
    const float* __restrict__ hs, const float* __restrict__ out_w,
    const float* __restrict__ out_b, float* __restrict__ ys)
{
    const int wave = threadIdx.x >> 6;
    const int lane = threadIdx.x & 63;
    const int r = blockIdx.x * 4 + wave;

    const float4* hv = (const float4*)(hs + (size_t)r * HH);
    const float4* wv = (const float4*)out_w;
    float acc = 0.f;
    #pragma unroll
    for (int i = 0; i < 2; ++i) {
        float4 h4 = hv[lane * 2 + i];
        float4 w4 = wv[lane * 2 + i];
        acc += h4.x * w4.x + h4.y * w4.y + h4.z * w4.z + h4.w * w4.w;
    }
    #pragma unroll
    for (int m = 32; m >= 1; m >>= 1) acc += __shfl_xor(acc, m, 64);
    if (lane == 0) ys[r] = acc + out_b[0];
}

extern "C" void kernel_launch(void* const* d_in, const int* in_sizes, int n_in,
                              void* d_out, int out_size, void* d_ws, size_t ws_size,
                              hipStream_t stream)
{
    const float* x    = (const float*)d_in[0];
    const float* Wi_w = (const float*)d_in[1];
    const float* Wi_b = (const float*)d_in[2];
    const float* Ui_w = (const float*)d_in[3];
    const float* Wf_w = (const float*)d_in[4];
    const float* Wf_b = (const float*)d_in[5];
    const float* Uf_w = (const float*)d_in[6];
    const float* Wo_w = (const float*)d_in[7];
    const float* Wo_b = (const float*)d_in[8];
    const float* Uo_w = (const float*)d_in[9];
    const float* Wg_w = (const float*)d_in[10];
    const float* Wg_b = (const float*)d_in[11];
    const float* Ug_w = (const float*)d_in[12];
    const float* out_w = (const float*)d_in[13];
    const float* out_b = (const float*)d_in[14];

    float* ys  = (float*)d_out;                     // [B*T]
    float* hs  = ys + (size_t)BB * TT;              // [B*T*H]
    float* fs  = hs + (size_t)BB * TT * HH;
    float* es  = fs + (size_t)BB * TT * HH;
    float* cds = es + (size_t)BB * TT * HH;

    // ws layout: [hT0 128KB][cnt 2KB][hT1 128KB][utT 4MB]
    float* hT0 = (float*)d_ws;
    int*   cnt = (int*)(hT0 + (size_t)HH * BB);
    float* hT1 = (float*)(cnt + TT);
    float* utT = hT1 + (size_t)HH * BB;

    // zero h0 + barrier counters every call (graph-replay safe)
    hipMemsetAsync(d_ws, 0, (size_t)HH * BB * sizeof(float) + TT * sizeof(int), stream);

    // U transpose for scalar-load path
    uT_kernel<<<NWG, 256, 0, stream>>>(Ui_w, Uf_w, Uo_w, Ug_w, utT);

    // Phase A: x projections into output buffers (scratch)
    xproj_kernel<<<256, 512, 0, stream>>>(x, Wi_w, Wi_b, Wf_w, Wf_b,
                                          Wo_w, Wo_b, Wg_w, Wg_b,
                                          hs, fs, es, cds);

    // Phase B: persistent recurrence
    lstm_persist<<<NWG, 512, 0, stream>>>(utT, Ui_w, Uf_w, Ug_w,
                                          hs, fs, es, cds, hT0, hT1, cnt);

    // Phase C: y projection
    lstm_y<<<(BB * TT) / 4, 256, 0, stream>>>(hs, out_w, out_b, ys);
}

// Round 4
// 8110.654 us; speedup vs baseline: 2.4082x; 1.1534x over previous
//
#include <hip/hip_runtime.h>
#include <math.h>

#define BB 64
#define TT 512
#define DD 128
#define HH 512
#define NWG 128

// ---------------------------------------------------------------------------
// Pre-kernel: transpose U into utT[quad][k][16], r = jp*4 + g, quad owns
// jj = quad*4 .. quad*4+3. Enables uniform (scalar) loads in the k-loop.
// ---------------------------------------------------------------------------
__global__ __launch_bounds__(256) void uT_kernel(
    const float* __restrict__ Ui_w, const float* __restrict__ Uf_w,
    const float* __restrict__ Uo_w, const float* __restrict__ Ug_w,
    float* __restrict__ utT)
{
    const int q = blockIdx.x;
    const int jj0 = q << 2;
    for (int k = threadIdx.x; k < HH; k += 256) {
        float v[16];
        #pragma unroll
        for (int r = 0; r < 16; ++r) {
            const int jp = r >> 2, g = r & 3;
            const float* U = (g == 0) ? Ui_w : (g == 1) ? Uf_w : (g == 2) ? Uo_w : Ug_w;
            v[r] = U[(size_t)(jj0 + jp) * HH + k];
        }
        float4* dst = (float4*)(utT + ((size_t)q * HH + k) * 16);
        dst[0] = make_float4(v[0], v[1], v[2], v[3]);
        dst[1] = make_float4(v[4], v[5], v[6], v[7]);
        dst[2] = make_float4(v[8], v[9], v[10], v[11]);
        dst[3] = make_float4(v[12], v[13], v[14], v[15]);
    }
}

// ---------------------------------------------------------------------------
// Phase A: x-projections (same as round 3). out[bt*HH + jj], bt = b*T + t.
// ---------------------------------------------------------------------------
__global__ __launch_bounds__(512) void xproj_kernel(
    const float* __restrict__ x,
    const float* __restrict__ Wi_w, const float* __restrict__ Wi_b,
    const float* __restrict__ Wf_w, const float* __restrict__ Wf_b,
    const float* __restrict__ Wo_w, const float* __restrict__ Wo_b,
    const float* __restrict__ Wg_w, const float* __restrict__ Wg_b,
    float* __restrict__ xi, float* __restrict__ xf,
    float* __restrict__ xo, float* __restrict__ xg)
{
    const int tid  = threadIdx.x;
    const int w    = tid >> 6;
    const int lane = tid & 63;
    const int g     = w >> 1;
    const int jhalf = w & 1;
    const int bt0   = blockIdx.x * 128;

    const float* W  = (g == 0) ? Wi_w : (g == 1) ? Wf_w : (g == 2) ? Wo_w : Wg_w;
    const float* Bv = (g == 0) ? Wi_b : (g == 1) ? Wf_b : (g == 2) ? Wo_b : Wg_b;
    float* out      = (g == 0) ? xi   : (g == 1) ? xf   : (g == 2) ? xo   : xg;

    for (int blk = 0; blk < 4; ++blk) {
        const int jj = jhalf * 256 + blk * 64 + lane;
        float4 wr[32];
        const float4* wsrc = (const float4*)(W + (size_t)jj * DD);
        #pragma unroll
        for (int i = 0; i < 32; ++i) wr[i] = wsrc[i];
        const float bias = Bv[jj];

        for (int bt = bt0; bt < bt0 + 128; ++bt) {
            const float4* xr = (const float4*)(x + (size_t)bt * DD);
            float acc = bias;
            #pragma unroll
            for (int i = 0; i < 32; ++i) {
                const float4 xv = xr[i];
                acc += xv.x * wr[i].x + xv.y * wr[i].y + xv.z * wr[i].z + xv.w * wr[i].w;
            }
            out[(size_t)bt * HH + jj] = acc;
        }
    }
}

// ---------------------------------------------------------------------------
// Persistent recurrence with per-jj generation flags (no global barrier).
// 128 WGs x 512 thr. WG owns quad = ((wg&7)<<4)|(wg>>3), jj0 = quad*4.
// Wave w covers k in [w*64, w*64+64). hT[2][HH][64] ping-pong + flags[2][HH].
// Producer: store h (agent) -> s_waitcnt vmcnt(0) -> store flag = t+1.
// Consumer: poll 64 flags of its k-slice (>= t), then 64 h loads, all in
// flight before the FMA loop. Outputs drained one step late by waves 4-7.
// ---------------------------------------------------------------------------
__global__ __launch_bounds__(512) void lstm_persist(
    const float* __restrict__ utT,
    const float* __restrict__ Ui_w, const float* __restrict__ Uf_w,
    const float* __restrict__ Ug_w,
    float* __restrict__ b_i, float* __restrict__ b_f,   // xi->hs, xf->fs
    float* __restrict__ b_o, float* __restrict__ b_g,   // xo->es, xg->cds
    float* __restrict__ hT,      // [2][HH][64]
    int*   __restrict__ flags)   // [2][HH]
{
    __shared__ float red[2][8][16][64];   // 64 KB, parity-double-buffered
    __shared__ float sh[2][4][64][4];     // 8 KB  [parity][arr][b][jp]

    const int tid  = threadIdx.x;
    const int w    = tid >> 6;
    const int lane = tid & 63;
    const int wg   = blockIdx.x;
    const int quad = ((wg & 7) << 4) | (wg >> 3);
    const int jj0  = quad << 2;
    const int k0   = w << 6;

    // wave-uniform scalar base for this wave's U slice
    const unsigned uoff = (unsigned)__builtin_amdgcn_readfirstlane(k0 << 4);
    const float4* up4 = (const float4*)(utT + (size_t)quad * (HH * 16) + uoff);

    float creg = 0.f, uid = 0.f, ufd = 0.f, ugd = 0.f;
    const int jp = (w < 4) ? w : 0;
    const int jj = jj0 + jp;
    if (w < 4) {
        uid = Ui_w[(size_t)jj * HH + jj];
        ufd = Uf_w[(size_t)jj * HH + jj];
        ugd = Ug_w[(size_t)jj * HH + jj];
    }

    for (int t = 0; t < TT; ++t) {
        const int p  = t & 1;
        const int np = p ^ 1;
        float* hsrc = hT + (size_t)p  * (HH * 64);
        float* hdst = hT + (size_t)np * (HH * 64);

        // ---- poll this wave's k-slice flags (gen t) ----
        {
            int fv;
            while (true) {
                fv = __hip_atomic_load(&flags[p * HH + k0 + lane],
                                       __ATOMIC_RELAXED, __HIP_MEMORY_SCOPE_AGENT);
                if (__all(fv >= t)) break;
                __builtin_amdgcn_s_sleep(1);
            }
        }

        // xp prefetch (waves 0-3): hidden under h-load + FMA
        float xpi = 0.f, xpf = 0.f, xpo = 0.f, xpg = 0.f;
        size_t adr = 0;
        if (w < 4) {
            adr = (size_t)lane * TT * HH + (size_t)t * HH + jj;
            xpi = b_i[adr]; xpf = b_f[adr]; xpo = b_o[adr]; xpg = b_g[adr];
        }

        // ---- issue ALL 64 h loads before the FMA loop (full MLP) ----
        float hreg[64];
        #pragma unroll
        for (int i = 0; i < 64; ++i)
            hreg[i] = __hip_atomic_load(&hsrc[((k0 + i) << 6) + lane],
                                        __ATOMIC_RELAXED, __HIP_MEMORY_SCOPE_AGENT);
        __builtin_amdgcn_sched_barrier(0);

        float acc[16];
        #pragma unroll
        for (int r = 0; r < 16; ++r) acc[r] = 0.f;

        #pragma unroll
        for (int i = 0; i < 64; ++i) {
            const float4 u0 = up4[(i << 2) + 0];
            const float4 u1 = up4[(i << 2) + 1];
            const float4 u2 = up4[(i << 2) + 2];
            const float4 u3 = up4[(i << 2) + 3];
            const float hv = hreg[i];
            acc[0]  = fmaf(u0.x, hv, acc[0]);
            acc[1]  = fmaf(u0.y, hv, acc[1]);
            acc[2]  = fmaf(u0.z, hv, acc[2]);
            acc[3]  = fmaf(u0.w, hv, acc[3]);
            acc[4]  = fmaf(u1.x, hv, acc[4]);
            acc[5]  = fmaf(u1.y, hv, acc[5]);
            acc[6]  = fmaf(u1.z, hv, acc[6]);
            acc[7]  = fmaf(u1.w, hv, acc[7]);
            acc[8]  = fmaf(u2.x, hv, acc[8]);
            acc[9]  = fmaf(u2.y, hv, acc[9]);
            acc[10] = fmaf(u2.z, hv, acc[10]);
            acc[11] = fmaf(u2.w, hv, acc[11]);
            acc[12] = fmaf(u3.x, hv, acc[12]);
            acc[13] = fmaf(u3.y, hv, acc[13]);
            acc[14] = fmaf(u3.z, hv, acc[14]);
            acc[15] = fmaf(u3.w, hv, acc[15]);
        }
        #pragma unroll
        for (int r = 0; r < 16; ++r) red[p][w][r][lane] = acc[r];
        __syncthreads();

        if (w < 4) {
            float pre[4];
            #pragma unroll
            for (int g = 0; g < 4; ++g) {
                float s = 0.f;
                #pragma unroll
                for (int wk = 0; wk < 8; ++wk) s += red[p][wk][(jp << 2) + g][lane];
                pre[g] = s;
            }
            const float pi = xpi + pre[0];
            const float pf = xpf + pre[1];
            const float po = xpo + pre[2];
            const float pg = xpg + pre[3];

            const float ig = __fdividef(1.f, 1.f + __expf(-pi));
            const float fg = __fdividef(1.f, 1.f + __expf(-pf));
            const float og = __fdividef(1.f, 1.f + __expf(-po));
            const float tg = __expf(-2.f * fmaxf(pg, -40.f));
            const float gg = __fdividef(1.f - tg, 1.f + tg);

            const float cp = creg;
            const float c  = fg * cp + ig * gg;
            creg = c;
            const float tc = __expf(-2.f * fmaxf(c, -40.f));
            const float th = __fdividef(1.f - tc, 1.f + tc);
            const float h  = og * th;
            const float e  = og * (1.f - th * th);
            const float cd = cp * (fg * (1.f - fg)) * ufd
                           + ig * (1.f - gg * gg) * ugd
                           + gg * (ig * (1.f - ig)) * uid;

            // publish h, then flag (release via vmcnt drain; h store is the
            // only outstanding VMEM op of consequence here)
            __hip_atomic_store(&hdst[(jj << 6) + lane], h,
                               __ATOMIC_RELAXED, __HIP_MEMORY_SCOPE_AGENT);
            asm volatile("s_waitcnt vmcnt(0)" ::: "memory");
            if (lane == 0)
                __hip_atomic_store(&flags[np * HH + jj], t + 1,
                                   __ATOMIC_RELAXED, __HIP_MEMORY_SCOPE_AGENT);

            // stage outputs for deferred drain by waves 4-7
            sh[p][0][lane][w] = h;
            sh[p][1][lane][w] = fg;
            sh[p][2][lane][w] = e;
            sh[p][3][lane][w] = cd;
        } else if (t > 0) {
            // drain gen t-1 outputs (sh[np], written at iter t-1 epilogue,
            // ordered by this iter's __syncthreads)
            const int arr = (tid - 256) >> 6;
            float* base = (arr == 0) ? b_i : (arr == 1) ? b_f : (arr == 2) ? b_o : b_g;
            const float4 v = *(const float4*)&sh[np][arr][lane][0];
            *(float4*)(base + (size_t)lane * TT * HH + (size_t)(t - 1) * HH + jj0) = v;
        }
    }

    // drain final step's outputs (gen TT-1 lives in sh[(TT-1)&1] = sh[1])
    __syncthreads();
    if (w >= 4) {
        const int arr = (tid - 256) >> 6;
        float* base = (arr == 0) ? b_i : (arr == 1) ? b_f : (arr == 2) ? b_o : b_g;
        const float4 v = *(const float4*)&sh[1][arr][lane][0];
        *(float4*)(base + (size_t)lane * TT * HH + (size_t)(TT - 1) * HH + jj0) = v;
    }
}

// ys[r] = dot(hs[r,:], out_w) + out_b ; one wave per row r = b*T + t
__global__ __launch_bounds__(256) void lstm_y(
    const float* __restrict__ hs, const float* __restrict__ out_w,
    const float* __restrict__ out_b, float* __restrict__ ys)
{
    const int wave = threadIdx.x >> 6;
    const int lane = threadIdx.x & 63;
    const int r = blockIdx.x * 4 + wave;

    const float4* hv = (const float4*)(hs + (size_t)r * HH);
    const float4* wv = (const float4*)out_w;
    float acc = 0.f;
    #pragma unroll
    for (int i = 0; i < 2; ++i) {
        float4 h4 = hv[lane * 2 + i];
        float4 w4 = wv[lane * 2 + i];
        acc += h4.x * w4.x + h4.y * w4.y + h4.z * w4.z + h4.w * w4.w;
    }
    #pragma unroll
    for (int m = 32; m >= 1; m >>= 1) acc += __shfl_xor(acc, m, 64);
    if (lane == 0) ys[r] = acc + out_b[0];
}

extern "C" void kernel_launch(void* const* d_in, const int* in_sizes, int n_in,
                              void* d_out, int out_size, void* d_ws, size_t ws_size,
                              hipStream_t stream)
{
    const float* x    = (const float*)d_in[0];
    const float* Wi_w = (const float*)d_in[1];
    const float* Wi_b = (const float*)d_in[2];
    const float* Ui_w = (const float*)d_in[3];
    const float* Wf_w = (const float*)d_in[4];
    const float* Wf_b = (const float*)d_in[5];
    const float* Uf_w = (const float*)d_in[6];
    const float* Wo_w = (const float*)d_in[7];
    const float* Wo_b = (const float*)d_in[8];
    const float* Uo_w = (const float*)d_in[9];
    const float* Wg_w = (const float*)d_in[10];
    const float* Wg_b = (const float*)d_in[11];
    const float* Ug_w = (const float*)d_in[12];
    const float* out_w = (const float*)d_in[13];
    const float* out_b = (const float*)d_in[14];

    float* ys  = (float*)d_out;                     // [B*T]
    float* hs  = ys + (size_t)BB * TT;              // [B*T*H]
    float* fs  = hs + (size_t)BB * TT * HH;
    float* es  = fs + (size_t)BB * TT * HH;
    float* cds = es + (size_t)BB * TT * HH;

    // ws layout: [hT 256KB][flags 4KB][utT 4MB]
    float* hT    = (float*)d_ws;
    int*   flags = (int*)(hT + (size_t)2 * HH * BB);
    float* utT   = (float*)(flags + 2 * HH);

    // zero hT (both parities) + flags every call (graph-replay safe)
    hipMemsetAsync(d_ws, 0,
                   (size_t)2 * HH * BB * sizeof(float) + 2 * HH * sizeof(int),
                   stream);

    // U transpose for scalar-load path
    uT_kernel<<<NWG, 256, 0, stream>>>(Ui_w, Uf_w, Uo_w, Ug_w, utT);

    // Phase A: x projections into output buffers (scratch)
    xproj_kernel<<<256, 512, 0, stream>>>(x, Wi_w, Wi_b, Wf_w, Wf_b,
                                          Wo_w, Wo_b, Wg_w, Wg_b,
                                          hs, fs, es, cds);

    // Phase B: persistent recurrence (dataflow, no global barrier)
    lstm_persist<<<NWG, 512, 0, stream>>>(utT, Ui_w, Uf_w, Ug_w,
                                          hs, fs, es, cds, hT, flags);

    // Phase C: y projection
    lstm_y<<<(BB * TT) / 4, 256, 0, stream>>>(hs, out_w, out_b, ys);
}

// Round 5
// 6350.238 us; speedup vs baseline: 3.0758x; 1.2772x over previous
//
#include <hip/hip_runtime.h>
#include <math.h>

#define BB 64
#define TT 512
#define DD 128
#define HH 512
#define NWG 128

// 8 agent-coherent loads, stride 256B, issued as one indivisible clause.
// volatile asm: IR cannot sink these into the FMA loop (round-4 failure mode).
#define LOAD8(d0,d1,d2,d3,d4,d5,d6,d7, ptr)                                   \
  asm volatile("global_load_dword %0, %8, off sc0 sc1\n\t"                    \
               "global_load_dword %1, %8, off offset:256 sc0 sc1\n\t"         \
               "global_load_dword %2, %8, off offset:512 sc0 sc1\n\t"         \
               "global_load_dword %3, %8, off offset:768 sc0 sc1\n\t"         \
               "global_load_dword %4, %8, off offset:1024 sc0 sc1\n\t"        \
               "global_load_dword %5, %8, off offset:1280 sc0 sc1\n\t"        \
               "global_load_dword %6, %8, off offset:1536 sc0 sc1\n\t"        \
               "global_load_dword %7, %8, off offset:1792 sc0 sc1"            \
               : "=v"(d0), "=v"(d1), "=v"(d2), "=v"(d3),                      \
                 "=v"(d4), "=v"(d5), "=v"(d6), "=v"(d7)                       \
               : "v"(ptr) : "memory")

// ---------------------------------------------------------------------------
// Pre-kernel: transpose U into utT[quad][k][16], r = jp*4 + g.
// ---------------------------------------------------------------------------
__global__ __launch_bounds__(256) void uT_kernel(
    const float* __restrict__ Ui_w, const float* __restrict__ Uf_w,
    const float* __restrict__ Uo_w, const float* __restrict__ Ug_w,
    float* __restrict__ utT)
{
    const int q = blockIdx.x;
    const int jj0 = q << 2;
    for (int k = threadIdx.x; k < HH; k += 256) {
        float v[16];
        #pragma unroll
        for (int r = 0; r < 16; ++r) {
            const int jp = r >> 2, g = r & 3;
            const float* U = (g == 0) ? Ui_w : (g == 1) ? Uf_w : (g == 2) ? Uo_w : Ug_w;
            v[r] = U[(size_t)(jj0 + jp) * HH + k];
        }
        float4* dst = (float4*)(utT + ((size_t)q * HH + k) * 16);
        dst[0] = make_float4(v[0], v[1], v[2], v[3]);
        dst[1] = make_float4(v[4], v[5], v[6], v[7]);
        dst[2] = make_float4(v[8], v[9], v[10], v[11]);
        dst[3] = make_float4(v[12], v[13], v[14], v[15]);
    }
}

// ---------------------------------------------------------------------------
// Phase A: x-projections. out[bt*HH + jj], bt = b*T + t.
// ---------------------------------------------------------------------------
__global__ __launch_bounds__(512) void xproj_kernel(
    const float* __restrict__ x,
    const float* __restrict__ Wi_w, const float* __restrict__ Wi_b,
    const float* __restrict__ Wf_w, const float* __restrict__ Wf_b,
    const float* __restrict__ Wo_w, const float* __restrict__ Wo_b,
    const float* __restrict__ Wg_w, const float* __restrict__ Wg_b,
    float* __restrict__ xi, float* __restrict__ xf,
    float* __restrict__ xo, float* __restrict__ xg)
{
    const int tid  = threadIdx.x;
    const int w    = tid >> 6;
    const int lane = tid & 63;
    const int g     = w >> 1;
    const int jhalf = w & 1;
    const int bt0   = blockIdx.x * 128;

    const float* W  = (g == 0) ? Wi_w : (g == 1) ? Wf_w : (g == 2) ? Wo_w : Wg_w;
    const float* Bv = (g == 0) ? Wi_b : (g == 1) ? Wf_b : (g == 2) ? Wo_b : Wg_b;
    float* out      = (g == 0) ? xi   : (g == 1) ? xf   : (g == 2) ? xo   : xg;

    for (int blk = 0; blk < 4; ++blk) {
        const int jj = jhalf * 256 + blk * 64 + lane;
        float4 wr[32];
        const float4* wsrc = (const float4*)(W + (size_t)jj * DD);
        #pragma unroll
        for (int i = 0; i < 32; ++i) wr[i] = wsrc[i];
        const float bias = Bv[jj];

        for (int bt = bt0; bt < bt0 + 128; ++bt) {
            const float4* xr = (const float4*)(x + (size_t)bt * DD);
            float acc = bias;
            #pragma unroll
            for (int i = 0; i < 32; ++i) {
                const float4 xv = xr[i];
                acc += xv.x * wr[i].x + xv.y * wr[i].y + xv.z * wr[i].z + xv.w * wr[i].w;
            }
            out[(size_t)bt * HH + jj] = acc;
        }
    }
}

// ---------------------------------------------------------------------------
// Persistent recurrence, per-jj generation flags, asm-forced h load clause.
// 128 WGs x 512 thr. WG owns quad = ((wg&7)<<4)|(wg>>3), jj0 = quad*4.
// Wave w covers k in [w*64, w*64+64). hT[2][HH][64] ping-pong + flags[2][HH].
// ---------------------------------------------------------------------------
__global__ __launch_bounds__(512, 2) void lstm_persist(
    const float* __restrict__ utT,
    const float* __restrict__ Ui_w, const float* __restrict__ Uf_w,
    const float* __restrict__ Ug_w,
    float* __restrict__ b_i, float* __restrict__ b_f,   // xi->hs, xf->fs
    float* __restrict__ b_o, float* __restrict__ b_g,   // xo->es, xg->cds
    float* __restrict__ hT,      // [2][HH][64]
    int*   __restrict__ flags)   // [2][HH]
{
    __shared__ float red[2][8][16][64];   // 64 KB, parity-double-buffered
    __shared__ float sh[2][4][64][4];     // 8 KB  [parity][arr][b][jp]

    const int tid  = threadIdx.x;
    const int w    = tid >> 6;
    const int lane = tid & 63;
    const int wg   = blockIdx.x;
    const int quad = ((wg & 7) << 4) | (wg >> 3);
    const int jj0  = quad << 2;
    const int k0   = w << 6;

    const unsigned uoff = (unsigned)__builtin_amdgcn_readfirstlane(k0 << 4);
    const float4* up4 = (const float4*)(utT + (size_t)quad * (HH * 16) + uoff);

    float creg = 0.f, uid = 0.f, ufd = 0.f, ugd = 0.f;
    const int jp = (w < 4) ? w : 0;
    const int jj = jj0 + jp;
    if (w < 4) {
        uid = Ui_w[(size_t)jj * HH + jj];
        ufd = Uf_w[(size_t)jj * HH + jj];
        ugd = Ug_w[(size_t)jj * HH + jj];
    }

    for (int t = 0; t < TT; ++t) {
        const int p  = t & 1;
        const int np = p ^ 1;
        const float* hsrc = hT + (size_t)p  * (HH * 64);
        float*       hdst = hT + (size_t)np * (HH * 64);

        // xp prefetch first: plain cached loads, in flight through the polls
        float xpi = 0.f, xpf = 0.f, xpo = 0.f, xpg = 0.f;
        size_t adr = 0;
        if (w < 4) {
            adr = (size_t)lane * TT * HH + (size_t)t * HH + jj;
            xpi = b_i[adr]; xpf = b_f[adr]; xpo = b_o[adr]; xpg = b_g[adr];
        }

        int* fbase = &flags[p * HH + k0];

        // ---- poll low-32 k flags, then launch first 32 loads ----
        {
            int fv;
            while (true) {
                fv = __hip_atomic_load(&fbase[lane], __ATOMIC_RELAXED,
                                       __HIP_MEMORY_SCOPE_AGENT);
                const unsigned long long b = __ballot(fv >= t);
                if ((b & 0xffffffffull) == 0xffffffffull) break;
                __builtin_amdgcn_s_sleep(1);
            }
        }

        float hreg[64];
        const char* hp = (const char*)(hsrc + (k0 << 6) + lane);
        LOAD8(hreg[0], hreg[1], hreg[2], hreg[3], hreg[4], hreg[5], hreg[6], hreg[7],  hp);
        LOAD8(hreg[8], hreg[9], hreg[10],hreg[11],hreg[12],hreg[13],hreg[14],hreg[15], hp + 2048);
        LOAD8(hreg[16],hreg[17],hreg[18],hreg[19],hreg[20],hreg[21],hreg[22],hreg[23], hp + 4096);
        LOAD8(hreg[24],hreg[25],hreg[26],hreg[27],hreg[28],hreg[29],hreg[30],hreg[31], hp + 6144);

        // ---- poll high-32 flags (chunk0 latency hides here) ----
        {
            int fv;
            while (true) {
                fv = __hip_atomic_load(&fbase[lane], __ATOMIC_RELAXED,
                                       __HIP_MEMORY_SCOPE_AGENT);
                if (__all(fv >= t)) break;
                __builtin_amdgcn_s_sleep(1);
            }
        }

        LOAD8(hreg[32],hreg[33],hreg[34],hreg[35],hreg[36],hreg[37],hreg[38],hreg[39], hp + 8192);
        LOAD8(hreg[40],hreg[41],hreg[42],hreg[43],hreg[44],hreg[45],hreg[46],hreg[47], hp + 10240);
        LOAD8(hreg[48],hreg[49],hreg[50],hreg[51],hreg[52],hreg[53],hreg[54],hreg[55], hp + 12288);
        LOAD8(hreg[56],hreg[57],hreg[58],hreg[59],hreg[60],hreg[61],hreg[62],hreg[63], hp + 14336);

        asm volatile("s_waitcnt vmcnt(0)" ::: "memory");
        __builtin_amdgcn_sched_barrier(0);

        float acc[16];
        #pragma unroll
        for (int r = 0; r < 16; ++r) acc[r] = 0.f;

        #pragma unroll
        for (int i = 0; i < 64; ++i) {
            const float4 u0 = up4[(i << 2) + 0];
            const float4 u1 = up4[(i << 2) + 1];
            const float4 u2 = up4[(i << 2) + 2];
            const float4 u3 = up4[(i << 2) + 3];
            const float hv = hreg[i];
            acc[0]  = fmaf(u0.x, hv, acc[0]);
            acc[1]  = fmaf(u0.y, hv, acc[1]);
            acc[2]  = fmaf(u0.z, hv, acc[2]);
            acc[3]  = fmaf(u0.w, hv, acc[3]);
            acc[4]  = fmaf(u1.x, hv, acc[4]);
            acc[5]  = fmaf(u1.y, hv, acc[5]);
            acc[6]  = fmaf(u1.z, hv, acc[6]);
            acc[7]  = fmaf(u1.w, hv, acc[7]);
            acc[8]  = fmaf(u2.x, hv, acc[8]);
            acc[9]  = fmaf(u2.y, hv, acc[9]);
            acc[10] = fmaf(u2.z, hv, acc[10]);
            acc[11] = fmaf(u2.w, hv, acc[11]);
            acc[12] = fmaf(u3.x, hv, acc[12]);
            acc[13] = fmaf(u3.y, hv, acc[13]);
            acc[14] = fmaf(u3.z, hv, acc[14]);
            acc[15] = fmaf(u3.w, hv, acc[15]);
        }
        #pragma unroll
        for (int r = 0; r < 16; ++r) red[p][w][r][lane] = acc[r];
        __syncthreads();

        if (w < 4) {
            float pre[4];
            #pragma unroll
            for (int g = 0; g < 4; ++g) {
                float s = 0.f;
                #pragma unroll
                for (int wk = 0; wk < 8; ++wk) s += red[p][wk][(jp << 2) + g][lane];
                pre[g] = s;
            }
            const float pi = xpi + pre[0];
            const float pf = xpf + pre[1];
            const float po = xpo + pre[2];
            const float pg = xpg + pre[3];

            const float ig = __fdividef(1.f, 1.f + __expf(-pi));
            const float fg = __fdividef(1.f, 1.f + __expf(-pf));
            const float og = __fdividef(1.f, 1.f + __expf(-po));
            const float tg = __expf(-2.f * fmaxf(pg, -40.f));
            const float gg = __fdividef(1.f - tg, 1.f + tg);

            const float cp = creg;
            const float c  = fg * cp + ig * gg;
            creg = c;
            const float tc = __expf(-2.f * fmaxf(c, -40.f));
            const float th = __fdividef(1.f - tc, 1.f + tc);
            const float h  = og * th;
            const float e  = og * (1.f - th * th);
            const float cd = cp * (fg * (1.f - fg)) * ufd
                           + ig * (1.f - gg * gg) * ugd
                           + gg * (ig * (1.f - ig)) * uid;

            // publish h then flag (release via vmcnt drain)
            __hip_atomic_store(&hdst[(jj << 6) + lane], h,
                               __ATOMIC_RELAXED, __HIP_MEMORY_SCOPE_AGENT);
            asm volatile("s_waitcnt vmcnt(0)" ::: "memory");
            if (lane == 0)
                __hip_atomic_store(&flags[np * HH + jj], t + 1,
                                   __ATOMIC_RELAXED, __HIP_MEMORY_SCOPE_AGENT);

            // stage outputs for deferred drain by waves 4-7
            sh[p][0][lane][w] = h;
            sh[p][1][lane][w] = fg;
            sh[p][2][lane][w] = e;
            sh[p][3][lane][w] = cd;
        } else if (t > 0) {
            // drain gen t-1 outputs (ordered by this iter's __syncthreads)
            const int arr = (tid - 256) >> 6;
            float* base = (arr == 0) ? b_i : (arr == 1) ? b_f : (arr == 2) ? b_o : b_g;
            const float4 v = *(const float4*)&sh[np][arr][lane][0];
            *(float4*)(base + (size_t)lane * TT * HH + (size_t)(t - 1) * HH + jj0) = v;
        }
    }

    // drain final step's outputs (gen TT-1 lives in sh[1])
    __syncthreads();
    if (w >= 4) {
        const int arr = (tid - 256) >> 6;
        float* base = (arr == 0) ? b_i : (arr == 1) ? b_f : (arr == 2) ? b_o : b_g;
        const float4 v = *(const float4*)&sh[1][arr][lane][0];
        *(float4*)(base + (size_t)lane * TT * HH + (size_t)(TT - 1) * HH + jj0) = v;
    }
}

// ys[r] = dot(hs[r,:], out_w) + out_b ; one wave per row r = b*T + t
__global__ __launch_bounds__(256) void lstm_y(
    const float* __restrict__ hs, const float* __restrict__ out_w,
    const float* __restrict__ out_b, float* __restrict__ ys)
{
    const int wave = threadIdx.x >> 6;
    const int lane = threadIdx.x & 63;
    const int r = blockIdx.x * 4 + wave;

    const float4* hv = (const float4*)(hs + (size_t)r * HH);
    const float4* wv = (const float4*)out_w;
    float acc = 0.f;
    #pragma unroll
    for (int i = 0; i < 2; ++i) {
        float4 h4 = hv[lane * 2 + i];
        float4 w4 = wv[lane * 2 + i];
        acc += h4.x * w4.x + h4.y * w4.y + h4.z * w4.z + h4.w * w4.w;
    }
    #pragma unroll
    for (int m = 32; m >= 1; m >>= 1) acc += __shfl_xor(acc, m, 64);
    if (lane == 0) ys[r] = acc + out_b[0];
}

extern "C" void kernel_launch(void* const* d_in, const int* in_sizes, int n_in,
                              void* d_out, int out_size, void* d_ws, size_t ws_size,
                              hipStream_t stream)
{
    const float* x    = (const float*)d_in[0];
    const float* Wi_w = (const float*)d_in[1];
    const float* Wi_b = (const float*)d_in[2];
    const float* Ui_w = (const float*)d_in[3];
    const float* Wf_w = (const float*)d_in[4];
    const float* Wf_b = (const float*)d_in[5];
    const float* Uf_w = (const float*)d_in[6];
    const float* Wo_w = (const float*)d_in[7];
    const float* Wo_b = (const float*)d_in[8];
    const float* Uo_w = (const float*)d_in[9];
    const float* Wg_w = (const float*)d_in[10];
    const float* Wg_b = (const float*)d_in[11];
    const float* Ug_w = (const float*)d_in[12];
    const float* out_w = (const float*)d_in[13];
    const float* out_b = (const float*)d_in[14];

    float* ys  = (float*)d_out;                     // [B*T]
    float* hs  = ys + (size_t)BB * TT;              // [B*T*H]
    float* fs  = hs + (size_t)BB * TT * HH;
    float* es  = fs + (size_t)BB * TT * HH;
    float* cds = es + (size_t)BB * TT * HH;

    // ws layout: [hT 256KB][flags 4KB][utT 4MB]
    float* hT    = (float*)d_ws;
    int*   flags = (int*)(hT + (size_t)2 * HH * BB);
    float* utT   = (float*)(flags + 2 * HH);

    // zero hT (both parities) + flags every call (graph-replay safe)
    hipMemsetAsync(d_ws, 0,
                   (size_t)2 * HH * BB * sizeof(float) + 2 * HH * sizeof(int),
                   stream);

    uT_kernel<<<NWG, 256, 0, stream>>>(Ui_w, Uf_w, Uo_w, Ug_w, utT);

    xproj_kernel<<<256, 512, 0, stream>>>(x, Wi_w, Wi_b, Wf_w, Wf_b,
                                          Wo_w, Wo_b, Wg_w, Wg_b,
                                          hs, fs, es, cds);

    lstm_persist<<<NWG, 512, 0, stream>>>(utT, Ui_w, Uf_w, Ug_w,
                                          hs, fs, es, cds, hT, flags);

    lstm_y<<<(BB * TT) / 4, 256, 0, stream>>>(hs, out_w, out_b, ys);
}